// Round 8
// baseline (197.941 us; speedup 1.0000x reference)
//
#include <hip/hip_runtime.h>

typedef __attribute__((ext_vector_type(8))) short short8;
typedef __attribute__((ext_vector_type(4))) short shortv4;
typedef __attribute__((ext_vector_type(4))) float f32x4;

#define B_      32
#define C_      128
#define H_      64
#define W_      64
#define OUT_    128
#define PLANE   4096
#define EWSZ    147456      // per-expert weight count

__device__ inline short f2bf(float f) {
    unsigned u = __builtin_bit_cast(unsigned, f);
    u += 0x7fff + ((u >> 16) & 1);
    return (short)(u >> 16);
}

// ---------------------------------------------------------------------------
// Kernel 1: adaptive avg pool -> pooled[b][c]
// ---------------------------------------------------------------------------
__global__ void pool_kernel(const float* __restrict__ x, float* __restrict__ pooled) {
    const int bc = blockIdx.x;
    const float4* plane = (const float4*)(x + (size_t)bc * PLANE);
    float s = 0.f;
#pragma unroll
    for (int i = 0; i < 4; ++i) {
        float4 v = plane[threadIdx.x + i * 256];
        s += v.x + v.y + v.z + v.w;
    }
#pragma unroll
    for (int off = 32; off > 0; off >>= 1) s += __shfl_down(s, off);
    __shared__ float ls[4];
    const int wave = threadIdx.x >> 6, lane = threadIdx.x & 63;
    if (lane == 0) ls[wave] = s;
    __syncthreads();
    if (threadIdx.x == 0)
        pooled[bc] = (ls[0] + ls[1] + ls[2] + ls[3]) * (1.f / 4096.f);
}

// ---------------------------------------------------------------------------
// Kernel 2: routing[b][e]
// ---------------------------------------------------------------------------
__global__ void routing_kernel(const float* __restrict__ pooled,
                               const float* __restrict__ rw,
                               const float* __restrict__ rb,
                               float* __restrict__ routing) {
    const int b = blockIdx.x;
    __shared__ float ps[C_];
    if (threadIdx.x < C_) ps[threadIdx.x] = pooled[b * C_ + threadIdx.x];
    __syncthreads();
    const int i = threadIdx.x;
    const float4* w4 = (const float4*)(rw + (size_t)i * C_);
    float z = rb[i];
#pragma unroll 8
    for (int c4 = 0; c4 < 32; ++c4) {
        float4 wv = w4[c4];
        z += wv.x * ps[c4 * 4 + 0] + wv.y * ps[c4 * 4 + 1]
           + wv.z * ps[c4 * 4 + 2] + wv.w * ps[c4 * 4 + 3];
    }
    float s = 1.f / (1.f + expf(-z));
#pragma unroll
    for (int off = 32; off > 0; off >>= 1) s += __shfl_down(s, off);
    if ((threadIdx.x & 63) == 0)
        routing[b * 4 + (threadIdx.x >> 6)] = s * (1.f / 64.f);
}

// ---------------------------------------------------------------------------
// Kernel 3a: epack — reorder raw ew into MFMA A-fragment order, fp32, ONCE
// (b-independent). epk[e][cc][ ((t*8+mf)*64+l)*8 + j ] =
//   ew[e][ (mf*16+(l&15))*1152 + (cc*32+(l>>4)*8+j)*9 + t ].
// Block = (os=mf, cc, e): stage the (16 o x 32 c x 9 t) slab in LDS
// (coalesced), scatter-read, write coalesced.
// ---------------------------------------------------------------------------
__global__ void epack_kernel(const float* __restrict__ ew, float* __restrict__ epk) {
    const int os = blockIdx.x;   // 0..7  = mf
    const int cc = blockIdx.y;   // 0..3
    const int e  = blockIdx.z;   // 0..3
    __shared__ float ls[16 * 292];
    const int tid = threadIdx.x;

    // stage: 16 rows of 288 contiguous floats = 1152 float4
    for (int idx = tid; idx < 1152; idx += 256) {
        const int i = idx / 72, q = idx % 72;
        float4 v = *(const float4*)(ew + (size_t)e * EWSZ
                     + (size_t)(os * 16 + i) * 1152 + cc * 288 + q * 4);
        *(float4*)&ls[i * 292 + q * 4] = v;
    }
    __syncthreads();

    // write: 1152 float4, coalesced; f4 idx = t*128 + r, r -> (l = r>>1, j0)
    float* outp = epk + ((size_t)e * 4 + cc) * 36864;
    for (int idx = tid; idx < 1152; idx += 256) {
        const int t = idx / 128, r = idx % 128;
        const int l = r >> 1, j0 = (r & 1) * 4;
        const int row = l & 15, cb = (l >> 4) * 8 + j0;
        float4 v;
        v.x = ls[row * 292 + (cb + 0) * 9 + t];
        v.y = ls[row * 292 + (cb + 1) * 9 + t];
        v.z = ls[row * 292 + (cb + 2) * 9 + t];
        v.w = ls[row * 292 + (cb + 3) * 9 + t];
        *(float4*)(outp + (size_t)(t * 8 + os) * 512 + r * 4) = v;
    }
}

// ---------------------------------------------------------------------------
// Kernel 3b: wmix — pure streaming: wbuf[b][n] = bf16( sum_e r[b][e]*epk[e][n] )
// All reads/writes fully coalesced; epk (2.4 MB) is L2/L3-hot.
// ---------------------------------------------------------------------------
__global__ void wmix_kernel(const float* __restrict__ rbuf,
                            const float* __restrict__ epk,
                            short* __restrict__ wbuf) {
#pragma unroll
    for (int it = 0; it < 2; ++it) {
        const int idx = blockIdx.x * 512 + it * 256 + threadIdx.x;  // < 1179648
        const int b = idx / 36864;              // 36864 float4 per sample
        const int r = idx - b * 36864;
        const float r0 = rbuf[b * 4 + 0], r1 = rbuf[b * 4 + 1];
        const float r2 = rbuf[b * 4 + 2], r3 = rbuf[b * 4 + 3];
        float4 a = *(const float4*)(epk + (size_t)r * 4);
        float4 bb = *(const float4*)(epk + 147456 + (size_t)r * 4);
        float4 c = *(const float4*)(epk + 2 * 147456 + (size_t)r * 4);
        float4 d = *(const float4*)(epk + 3 * 147456 + (size_t)r * 4);
        shortv4 v;
        v[0] = f2bf(r0 * a.x + r1 * bb.x + r2 * c.x + r3 * d.x);
        v[1] = f2bf(r0 * a.y + r1 * bb.y + r2 * c.y + r3 * d.y);
        v[2] = f2bf(r0 * a.z + r1 * bb.z + r2 * c.z + r3 * d.z);
        v[3] = f2bf(r0 * a.w + r1 * bb.w + r2 * c.w + r3 * d.w);
        *(shortv4*)(wbuf + (size_t)b * 147456 + (size_t)r * 4) = v;
    }
}

// ---------------------------------------------------------------------------
// Kernel 4: MFMA conv. Block = (b, 4 rows, 128 o), 4 waves (wave = 1 row).
// Grid (32,16) = 512 blocks = 2 blocks/CU.  LDS 72.6 KB: xs [6][66][40] bf16
// + ws = ONE tap-part (4 or 5 taps) of A-frags, staged via global_load_lds.
// K loop: 4 c-chunks x 2 tap-parts; X reg-prefetched (bf16) one chunk ahead.
// ---------------------------------------------------------------------------
__global__ __launch_bounds__(256, 2) void conv_kernel(const float* __restrict__ x,
                                                      const short* __restrict__ wbuf,
                                                      float* __restrict__ out) {
    __shared__ __attribute__((aligned(16))) short xs_s[15840];  // [6][66][40] = 31680 B
    __shared__ __attribute__((aligned(16))) short ws_s[20480];  // 40960 B (5-tap part)

    const int b = blockIdx.x, hb = blockIdx.y;
    const int h0 = hb * 4;
    const int tid = threadIdx.x;
    const int wid = tid >> 6, lane = tid & 63;
    const int ln15 = lane & 15, lg = lane >> 4;

    // zero xs once: cols 0 and 65 (w = -1, 64) stay zero forever
    for (int i = tid; i < 7920; i += 256) ((int*)xs_s)[i] = 0;

    f32x4 acc[8][4];
#pragma unroll
    for (int m = 0; m < 8; ++m)
#pragma unroll
        for (int n = 0; n < 4; ++n) acc[m][n] = (f32x4){0.f, 0.f, 0.f, 0.f};

    const float* xb = x + (size_t)b * C_ * PLANE;
    const short* wsrc_b = wbuf + (size_t)b * 4 * 36864;

    // X staging tasks: 1536 = 6 x 256: (w 64) x (row 6) x (cgroup 4)
    int tw[6], tr[6], tcg[6], trow[6];
#pragma unroll
    for (int it = 0; it < 6; ++it) {
        const int task = it * 256 + tid;
        tw[it] = task & 63;
        const int rc = task >> 6;
        tr[it] = rc % 6;
        tcg[it] = rc / 6;
        trow[it] = h0 - 1 + tr[it];
    }

    short8 xpre[6];
#define LOADX(CCC)                                                              \
    {                                                                           \
        _Pragma("unroll")                                                       \
        for (int it = 0; it < 6; ++it) {                                        \
            const bool valid = (unsigned)trow[it] < 64u;                        \
            const float* src = xb + (size_t)((CCC) * 32 + tcg[it] * 8) * PLANE  \
                             + trow[it] * 64 + tw[it];                          \
            short8 v;                                                           \
            _Pragma("unroll")                                                   \
            for (int k = 0; k < 8; ++k)                                         \
                v[k] = f2bf(valid ? src[(size_t)k * PLANE] : 0.f);              \
            xpre[it] = v;                                                       \
        }                                                                       \
    }

#define DO_TAP(TL, T)                                                           \
    {                                                                           \
        const int kh = (T) / 3, kw = (T) % 3;                                   \
        short8 bfr[4];                                                          \
        _Pragma("unroll")                                                       \
        for (int nf = 0; nf < 4; ++nf)                                          \
            bfr[nf] = *(const short8*)&xs_s[((wid + kh) * 66 + nf * 16 + ln15 + kw) * 40 + lg * 8]; \
        _Pragma("unroll")                                                       \
        for (int mf = 0; mf < 8; ++mf) {                                        \
            short8 af = *(const short8*)&ws_s[(((TL) * 8 + mf) * 64 + lane) * 8]; \
            _Pragma("unroll")                                                   \
            for (int nf = 0; nf < 4; ++nf)                                      \
                acc[mf][nf] = __builtin_amdgcn_mfma_f32_16x16x32_bf16(          \
                    af, bfr[nf], acc[mf][nf], 0, 0, 0);                         \
        }                                                                       \
    }

    LOADX(0);
    __syncthreads();   // zero-init of xs visible

    for (int cc = 0; cc < 4; ++cc) {
        // ---- write X tile (bf16, c-contiguous) ----
#pragma unroll
        for (int it = 0; it < 6; ++it)
            *(short8*)&xs_s[((tr[it] * 66) + 1 + tw[it]) * 40 + tcg[it] * 8] = xpre[it];

        const char* srcb = (const char*)(wsrc_b + (size_t)cc * 36864);
        // ---- stage ws part0: taps 0..3 (32768 B) ----
#pragma unroll
        for (int it = 0; it < 8; ++it) {
            const int off = (wid * 8 + it) * 1024 + lane * 16;
            __builtin_amdgcn_global_load_lds(
                (const __attribute__((address_space(1))) void*)(srcb + off),
                (__attribute__((address_space(3))) void*)(((char*)ws_s) + off), 16, 0, 0);
        }
        __syncthreads();   // xs visible + part0 ready

        DO_TAP(0, 0) DO_TAP(1, 1) DO_TAP(2, 2) DO_TAP(3, 3)
        __syncthreads();   // compute done before ws overwrite

        // ---- stage ws part1: taps 4..8 (40960 B) ----
#pragma unroll
        for (int it = 0; it < 10; ++it) {
            const int off = (wid * 10 + it) * 1024 + lane * 16;
            __builtin_amdgcn_global_load_lds(
                (const __attribute__((address_space(1))) void*)(srcb + 32768 + off),
                (__attribute__((address_space(3))) void*)(((char*)ws_s) + off), 16, 0, 0);
        }
        __syncthreads();   // part1 ready

        // prefetch next chunk's X (overlaps with part1 compute)
        if (cc < 3) LOADX(cc + 1);

        DO_TAP(0, 4) DO_TAP(1, 5) DO_TAP(2, 6) DO_TAP(3, 7) DO_TAP(4, 8)
        __syncthreads();   // done before next cc's xs/ws writes
    }

    // ---- epilogue: C/D col = lane&15 (px), row = (lane>>4)*4+q (o) ----
    float* ob = out + (size_t)b * OUT_ * PLANE;
    const int h = h0 + wid;
#pragma unroll
    for (int mf = 0; mf < 8; ++mf) {
#pragma unroll
        for (int nf = 0; nf < 4; ++nf) {
            const int w = nf * 16 + ln15;
            const int o0 = mf * 16 + lg * 4;
#pragma unroll
            for (int q = 0; q < 4; ++q)
                ob[((size_t)(o0 + q) * 64 + h) * 64 + w] = acc[mf][nf][q];
        }
    }
#undef LOADX
#undef DO_TAP
}

// ---------------------------------------------------------------------------
extern "C" void kernel_launch(void* const* d_in, const int* in_sizes, int n_in,
                              void* d_out, int out_size, void* d_ws, size_t ws_size,
                              hipStream_t stream) {
    const float* x  = (const float*)d_in[0];   // [32,128,64,64]
    const float* rw = (const float*)d_in[1];   // [256,128]
    const float* rb = (const float*)d_in[2];   // [256]
    const float* ew = (const float*)d_in[3];   // [4,147456]
    float* out = (float*)d_out;                // [32,128,64,64]

    float* pooled  = (float*)d_ws;             // 4096 floats
    float* routing = pooled + 4096;            // 128 floats (pad to 8192)
    float* epk     = pooled + 8192;            // 589824 floats (frag-ordered experts)
    short* wbuf    = (short*)(epk + 589824);   // 4718592 bf16 (9.4 MB)

    epack_kernel<<<dim3(8, 4, 4), 256, 0, stream>>>(ew, epk);
    pool_kernel<<<dim3(B_ * C_), 256, 0, stream>>>(x, pooled);
    routing_kernel<<<dim3(B_), 256, 0, stream>>>(pooled, rw, rb, routing);
    wmix_kernel<<<dim3(2304), 256, 0, stream>>>(routing, epk, wbuf);
    // grid (b, hb): linear id = b + 32*hb -> XCD = b%8 (per-sample L2 locality)
    conv_kernel<<<dim3(B_, 16), 256, 0, stream>>>(x, wbuf, out);
}

// Round 11
// 166.521 us; speedup vs baseline: 1.1887x; 1.1887x over previous
//
#include <hip/hip_runtime.h>

typedef __attribute__((ext_vector_type(8))) short short8;
typedef __attribute__((ext_vector_type(4))) short shortv4;
typedef __attribute__((ext_vector_type(4))) float f32x4;

#define B_      32
#define C_      128
#define H_      64
#define W_      64
#define OUT_    128
#define PLANE   4096
#define EWSZ    147456      // per-expert weight count

__device__ inline short f2bf(float f) {
    unsigned u = __builtin_bit_cast(unsigned, f);
    u += 0x7fff + ((u >> 16) & 1);
    return (short)(u >> 16);
}

// ---------------------------------------------------------------------------
// Kernel 1: adaptive avg pool -> pooled[b][c]
// ---------------------------------------------------------------------------
__global__ void pool_kernel(const float* __restrict__ x, float* __restrict__ pooled) {
    const int bc = blockIdx.x;
    const float4* plane = (const float4*)(x + (size_t)bc * PLANE);
    float s = 0.f;
#pragma unroll
    for (int i = 0; i < 4; ++i) {
        float4 v = plane[threadIdx.x + i * 256];
        s += v.x + v.y + v.z + v.w;
    }
#pragma unroll
    for (int off = 32; off > 0; off >>= 1) s += __shfl_down(s, off);
    __shared__ float ls[4];
    const int wave = threadIdx.x >> 6, lane = threadIdx.x & 63;
    if (lane == 0) ls[wave] = s;
    __syncthreads();
    if (threadIdx.x == 0)
        pooled[bc] = (ls[0] + ls[1] + ls[2] + ls[3]) * (1.f / 4096.f);
}

// ---------------------------------------------------------------------------
// Kernel 2: routing[b][e]
// ---------------------------------------------------------------------------
__global__ void routing_kernel(const float* __restrict__ pooled,
                               const float* __restrict__ rw,
                               const float* __restrict__ rb,
                               float* __restrict__ routing) {
    const int b = blockIdx.x;
    __shared__ float ps[C_];
    if (threadIdx.x < C_) ps[threadIdx.x] = pooled[b * C_ + threadIdx.x];
    __syncthreads();
    const int i = threadIdx.x;
    const float4* w4 = (const float4*)(rw + (size_t)i * C_);
    float z = rb[i];
#pragma unroll 8
    for (int c4 = 0; c4 < 32; ++c4) {
        float4 wv = w4[c4];
        z += wv.x * ps[c4 * 4 + 0] + wv.y * ps[c4 * 4 + 1]
           + wv.z * ps[c4 * 4 + 2] + wv.w * ps[c4 * 4 + 3];
    }
    float s = 1.f / (1.f + expf(-z));
#pragma unroll
    for (int off = 32; off > 0; off >>= 1) s += __shfl_down(s, off);
    if ((threadIdx.x & 63) == 0)
        routing[b * 4 + (threadIdx.x >> 6)] = s * (1.f / 64.f);
}

// ---------------------------------------------------------------------------
// Kernel 3a: epack — reorder raw ew into MFMA A-fragment order, fp32, once.
// ---------------------------------------------------------------------------
__global__ void epack_kernel(const float* __restrict__ ew, float* __restrict__ epk) {
    const int os = blockIdx.x;   // 0..7  = mf
    const int cc = blockIdx.y;   // 0..3
    const int e  = blockIdx.z;   // 0..3
    __shared__ float ls[16 * 292];
    const int tid = threadIdx.x;

    for (int idx = tid; idx < 1152; idx += 256) {
        const int i = idx / 72, q = idx % 72;
        float4 v = *(const float4*)(ew + (size_t)e * EWSZ
                     + (size_t)(os * 16 + i) * 1152 + cc * 288 + q * 4);
        *(float4*)&ls[i * 292 + q * 4] = v;
    }
    __syncthreads();

    float* outp = epk + ((size_t)e * 4 + cc) * 36864;
    for (int idx = tid; idx < 1152; idx += 256) {
        const int t = idx / 128, r = idx % 128;
        const int l = r >> 1, j0 = (r & 1) * 4;
        const int row = l & 15, cb = (l >> 4) * 8 + j0;
        float4 v;
        v.x = ls[row * 292 + (cb + 0) * 9 + t];
        v.y = ls[row * 292 + (cb + 1) * 9 + t];
        v.z = ls[row * 292 + (cb + 2) * 9 + t];
        v.w = ls[row * 292 + (cb + 3) * 9 + t];
        *(float4*)(outp + (size_t)(t * 8 + os) * 512 + r * 4) = v;
    }
}

// ---------------------------------------------------------------------------
// Kernel 3b: wmix — streaming expert mix, bf16 out, all coalesced.
// ---------------------------------------------------------------------------
__global__ void wmix_kernel(const float* __restrict__ rbuf,
                            const float* __restrict__ epk,
                            short* __restrict__ wbuf) {
#pragma unroll
    for (int it = 0; it < 2; ++it) {
        const int idx = blockIdx.x * 512 + it * 256 + threadIdx.x;
        const int b = idx / 36864;
        const int r = idx - b * 36864;
        const float r0 = rbuf[b * 4 + 0], r1 = rbuf[b * 4 + 1];
        const float r2 = rbuf[b * 4 + 2], r3 = rbuf[b * 4 + 3];
        float4 a = *(const float4*)(epk + (size_t)r * 4);
        float4 bb = *(const float4*)(epk + 147456 + (size_t)r * 4);
        float4 c = *(const float4*)(epk + 2 * 147456 + (size_t)r * 4);
        float4 d = *(const float4*)(epk + 3 * 147456 + (size_t)r * 4);
        shortv4 v;
        v[0] = f2bf(r0 * a.x + r1 * bb.x + r2 * c.x + r3 * d.x);
        v[1] = f2bf(r0 * a.y + r1 * bb.y + r2 * c.y + r3 * d.y);
        v[2] = f2bf(r0 * a.z + r1 * bb.z + r2 * c.z + r3 * d.z);
        v[3] = f2bf(r0 * a.w + r1 * bb.w + r2 * c.w + r3 * d.w);
        *(shortv4*)(wbuf + (size_t)b * 147456 + (size_t)r * 4) = v;
    }
}

// ---------------------------------------------------------------------------
// Kernel 4: MFMA conv, software-pipelined W stream.
// Block = (b, 8 rows, 128 o), 8 waves (wave = 1 h-row). Grid (32,8) = 1/CU.
// W split: 4 c-chunks x 3 tap-parts (3 taps each, 24576 B), DOUBLE-BUFFERED;
// part p+1 is issued right after the barrier preceding part p's MFMA, so the
// next barrier's vmcnt(0) drain finds it ~1 MFMA-part old (L2 latency hidden).
// X: raw fp32 regs prefetched mid-chunk, cvt+written at chunk boundary.
// LDS = 52800 (xs [10][66][40]) + 2*24576 (ws) = 101952 B -> 1 block/CU.
// ---------------------------------------------------------------------------
__global__ __launch_bounds__(512, 2) void conv_kernel(const float* __restrict__ x,
                                                      const short* __restrict__ wbuf,
                                                      float* __restrict__ out) {
    __shared__ __attribute__((aligned(16))) short xs_s[26400];      // [10][66][40]
    __shared__ __attribute__((aligned(16))) short ws_s[2][12288];   // 2 x 24576 B

    const int b = blockIdx.x, hb = blockIdx.y;
    const int h0 = hb * 8;
    const int tid = threadIdx.x;
    const int wid = tid >> 6, lane = tid & 63;
    const int ln15 = lane & 15, lg = lane >> 4;

    for (int i = tid; i < 13200; i += 512) ((int*)xs_s)[i] = 0;

    f32x4 acc[8][4];
#pragma unroll
    for (int m = 0; m < 8; ++m)
#pragma unroll
        for (int n = 0; n < 4; ++n) acc[m][n] = (f32x4){0.f, 0.f, 0.f, 0.f};

    const float* xb = x + (size_t)b * C_ * PLANE;
    const char* wsrc_b = (const char*)(wbuf + (size_t)b * 4 * 36864);

    // X staging tasks: 2560 = 64 w x 10 rows x 4 cgroups; 5 per thread.
    int tw[5], tr[5], tcg[5];
    bool tvalid[5];
    const float* tsrc[5];
#pragma unroll
    for (int it = 0; it < 5; ++it) {
        const int task = it * 512 + tid;
        tw[it] = task & 63;
        const int rc = task >> 6;
        tr[it] = rc % 10;
        tcg[it] = rc / 10;
        const int trow = h0 - 1 + tr[it];
        tvalid[it] = (unsigned)trow < 64u;
        const int rowc = trow < 0 ? 0 : (trow > 63 ? 63 : trow);
        tsrc[it] = xb + (size_t)(tcg[it] * 8) * PLANE + rowc * 64 + tw[it];
    }

    float xraw[5][8];
#define LOADX(CC)                                                               \
    {                                                                           \
        _Pragma("unroll")                                                       \
        for (int it = 0; it < 5; ++it)                                          \
            _Pragma("unroll")                                                   \
            for (int k = 0; k < 8; ++k)                                         \
                xraw[it][k] = tsrc[it][(size_t)((CC) * 32 + k) * PLANE];        \
    }
#define WRITE_XS()                                                              \
    {                                                                           \
        _Pragma("unroll")                                                       \
        for (int it = 0; it < 5; ++it) {                                        \
            short8 v;                                                           \
            _Pragma("unroll")                                                   \
            for (int k = 0; k < 8; ++k)                                         \
                v[k] = tvalid[it] ? f2bf(xraw[it][k]) : (short)0;               \
            *(short8*)&xs_s[((tr[it] * 66) + 1 + tw[it]) * 40 + tcg[it] * 8] = v; \
        }                                                                       \
    }
    // W part stage: 24576 B via global_load_lds width-16, linear (wid*3+it<24)
#define STAGE(BUF, CC, PART)                                                    \
    {                                                                           \
        const char* srcp = wsrc_b + (CC) * 73728 + (PART) * 24576;              \
        char* dstp = (char*)(&ws_s[BUF][0]);                                    \
        _Pragma("unroll")                                                       \
        for (int it = 0; it < 3; ++it) {                                        \
            const int off = (wid * 3 + it) * 1024 + lane * 16;                  \
            __builtin_amdgcn_global_load_lds(                                   \
                (const __attribute__((address_space(1))) void*)(srcp + off),    \
                (__attribute__((address_space(3))) void*)(dstp + off), 16, 0, 0); \
        }                                                                       \
    }
#define DO_TAP(BUF, TL, T)                                                      \
    {                                                                           \
        const int kh = (T) / 3, kw = (T) % 3;                                   \
        short8 bfr[4];                                                          \
        _Pragma("unroll")                                                       \
        for (int nf = 0; nf < 4; ++nf)                                          \
            bfr[nf] = *(const short8*)&xs_s[((wid + kh) * 66 + nf * 16 + ln15 + kw) * 40 + lg * 8]; \
        _Pragma("unroll")                                                       \
        for (int mf = 0; mf < 8; ++mf) {                                        \
            short8 af = *(const short8*)&ws_s[BUF][(((TL) * 8 + mf) * 64 + lane) * 8]; \
            _Pragma("unroll")                                                   \
            for (int nf = 0; nf < 4; ++nf)                                      \
                acc[mf][nf] = __builtin_amdgcn_mfma_f32_16x16x32_bf16(          \
                    af, bfr[nf], acc[mf][nf], 0, 0, 0);                         \
        }                                                                       \
    }
#define DO_PART(BUF, T0)                                                        \
    __builtin_amdgcn_s_setprio(1);                                              \
    DO_TAP(BUF, 0, (T0) + 0) DO_TAP(BUF, 1, (T0) + 1) DO_TAP(BUF, 2, (T0) + 2) \
    __builtin_amdgcn_s_setprio(0);

    // ---- prologue ----
    LOADX(0);
    STAGE(0, 0, 0);                      // W part (cc0,p0) -> buf0
    __syncthreads();                      // zeros visible; X0+W0 drained (once)
    WRITE_XS();
    STAGE(1, 0, 1);                      // W (cc0,p1) -> buf1
    __syncthreads();                      // xs0 visible; W1 drained (short hide)

    // ---- 4 chunks x 3 parts, double-buffered, issue-one-ahead ----
#define CHUNK(CC, BA, BB)                                                       \
    DO_PART(BA, 0)                       /* part0: taps 0-2 */                  \
    __syncthreads();                                                            \
    STAGE(BA, CC, 2);                    /* W(cc,p2) -> BA */                   \
    if ((CC) < 3) LOADX((CC) + 1);                                              \
    __builtin_amdgcn_sched_barrier(0);                                          \
    DO_PART(BB, 3)                       /* part1: taps 3-5 */                  \
    __syncthreads();                                                            \
    if ((CC) < 3) STAGE(BB, (CC) + 1, 0); /* W(cc+1,p0) -> BB */                \
    __builtin_amdgcn_sched_barrier(0);                                          \
    DO_PART(BA, 6)                       /* part2: taps 6-8 */                  \
    __syncthreads();                                                            \
    if ((CC) < 3) {                                                             \
        WRITE_XS();                                                             \
        STAGE(BA, (CC) + 1, 1);          /* W(cc+1,p1) -> BA */                 \
        __syncthreads();                                                        \
    }

    CHUNK(0, 0, 1)
    CHUNK(1, 1, 0)
    CHUNK(2, 0, 1)
    CHUNK(3, 1, 0)

    // ---- epilogue: C/D col = lane&15 (px), row = (lane>>4)*4+q (o) ----
    float* ob = out + (size_t)b * OUT_ * PLANE;
    const int h = h0 + wid;
#pragma unroll
    for (int mf = 0; mf < 8; ++mf) {
#pragma unroll
        for (int nf = 0; nf < 4; ++nf) {
            const int w = nf * 16 + ln15;
            const int o0 = mf * 16 + lg * 4;
#pragma unroll
            for (int q = 0; q < 4; ++q)
                ob[((size_t)(o0 + q) * 64 + h) * 64 + w] = acc[mf][nf][q];
        }
    }
#undef LOADX
#undef WRITE_XS
#undef STAGE
#undef DO_TAP
#undef DO_PART
#undef CHUNK
}

// ---------------------------------------------------------------------------
extern "C" void kernel_launch(void* const* d_in, const int* in_sizes, int n_in,
                              void* d_out, int out_size, void* d_ws, size_t ws_size,
                              hipStream_t stream) {
    const float* x  = (const float*)d_in[0];   // [32,128,64,64]
    const float* rw = (const float*)d_in[1];   // [256,128]
    const float* rb = (const float*)d_in[2];   // [256]
    const float* ew = (const float*)d_in[3];   // [4,147456]
    float* out = (float*)d_out;                // [32,128,64,64]

    float* pooled  = (float*)d_ws;             // 4096 floats
    float* routing = pooled + 4096;            // 128 floats (pad to 8192)
    float* epk     = pooled + 8192;            // 589824 floats
    short* wbuf    = (short*)(epk + 589824);   // 4718592 bf16 (9.4 MB)

    epack_kernel<<<dim3(8, 4, 4), 256, 0, stream>>>(ew, epk);
    pool_kernel<<<dim3(B_ * C_), 256, 0, stream>>>(x, pooled);
    routing_kernel<<<dim3(B_), 256, 0, stream>>>(pooled, rw, rb, routing);
    wmix_kernel<<<dim3(2304), 256, 0, stream>>>(routing, epk, wbuf);
    // grid (b, hb): linear id = b + 32*hb -> XCD = b%8 (per-sample L2 locality)
    conv_kernel<<<dim3(B_, 8), 512, 0, stream>>>(x, wbuf, out);
}